// Round 4
// baseline (220.837 us; speedup 1.0000x reference)
//
#include <hip/hip_runtime.h>
#include <hip/hip_bf16.h>
#include <stdint.h>

typedef unsigned short u16;
typedef unsigned int u32;
typedef __attribute__((ext_vector_type(4))) float f32x4;
typedef __attribute__((ext_vector_type(8))) short bf16x8;
typedef __attribute__((ext_vector_type(4))) unsigned int u32x4;
typedef __attribute__((ext_vector_type(2))) unsigned int u32x2;

#define DEV __device__ __forceinline__

DEV u16 f2bf(float f) {
  union { float f; uint32_t u; } v; v.f = f;
  uint32_t u = v.u;
  return (u16)((u + 0x7fffu + ((u >> 16) & 1u)) >> 16);
}
DEV float bf2f(u16 h) {
  union { uint32_t u; float f; } v; v.u = ((uint32_t)h) << 16;
  return v.f;
}

DEV void gload_lds16(const u16* g, u16* l) {
  __builtin_amdgcn_global_load_lds(
      (const __attribute__((address_space(1))) void*)g,
      (__attribute__((address_space(3))) void*)l, 16, 0, 0);
}

// DPP rotate within 16-lane rows (VALU pipe, replaces ds_bpermute shuffles)
template <int CTRL>
DEV float dppf(float v) {
  int r = __builtin_amdgcn_update_dpp(0, __builtin_bit_cast(int, v), CTRL, 0xf, 0xf, false);
  return __builtin_bit_cast(float, r);
}
DEV float rmax16(float v) {
  v = fmaxf(v, dppf<0x128>(v));  // row_ror:8
  v = fmaxf(v, dppf<0x124>(v));  // row_ror:4
  v = fmaxf(v, dppf<0x122>(v));  // row_ror:2
  v = fmaxf(v, dppf<0x121>(v));  // row_ror:1
  return v;
}
DEV float rsum16(float v) {
  v += dppf<0x128>(v);
  v += dppf<0x124>(v);
  v += dppf<0x122>(v);
  v += dppf<0x121>(v);
  return v;
}

// ---------------- prep: fp32 -> bf16 + transposed weights ----------------
__global__ __launch_bounds__(256) void prep_kernel(
    const float* __restrict__ Q, const float* __restrict__ K, const float* __restrict__ V,
    const float* __restrict__ WQ, const float* __restrict__ WK, const float* __restrict__ WV,
    const float* __restrict__ WO,
    u16* __restrict__ Qb, u16* __restrict__ Kb, u16* __restrict__ Vb,
    u16* __restrict__ Wt, u16* __restrict__ Wot) {
  const int i = blockIdx.x * 256 + threadIdx.x;  // 1,048,576 threads
#pragma unroll
  for (int it = 0; it < 3; ++it) {
    int idx = it * 1048576 + i;
    int which = idx >> 20, j = idx & 1048575;
    const float* src = which == 0 ? Q : (which == 1 ? K : V);
    u16* dst = which == 0 ? Qb : (which == 1 ? Kb : Vb);
    float4 v = ((const float4*)src)[j];
    u32x2 pk;
    pk[0] = (u32)f2bf(v.x) | ((u32)f2bf(v.y) << 16);
    pk[1] = (u32)f2bf(v.z) | ((u32)f2bf(v.w) << 16);
    *(u32x2*)(dst + (size_t)j * 4) = pk;
  }
#pragma unroll
  for (int it = 0; it < 4; ++it) {
    int idx = it * 1048576 + i;
    if (idx < 3145728) {
      int p = idx >> 20, r = idx & 1048575;
      int n = r >> 10, d = r & 1023;
      int h = n >> 6, k = n & 63;
      const float* src = p == 0 ? WQ : (p == 1 ? WK : WV);
      Wt[idx] = f2bf(src[(h * 1024 + d) * 64 + k]);
    } else {
      int j = idx - 3145728;
      int c = j >> 10, k = j & 1023;
      Wot[j] = f2bf(WO[k * 1024 + c]);
    }
  }
}

// ---------------- GEMM: C[4096][1024] = A[4096][1024] * Bt^T, z-batched ----------------
template <int OUT_BF16>
__global__ __launch_bounds__(256, 2) void gemm_kernel(const u16* __restrict__ A,
                                                      const u16* __restrict__ Bt,
                                                      void* __restrict__ Cout) {
  __shared__ __align__(16) u16 Alds[128 * 64];
  __shared__ __align__(16) u16 Blds[128 * 64];
  const size_t zo = blockIdx.z;
  A += zo * 4194304;
  Bt += zo * 1048576;
  const int tid = threadIdx.x;
  const int l = tid & 63, w = tid >> 6;
  const int wm = w >> 1, wn = w & 1;
  const int tileM = blockIdx.x * 128, tileN = blockIdx.y * 128;
  const int lr = l >> 3, lch = l & 7;

  f32x4 acc[4][4] = {};

  for (int kt = 0; kt < 16; ++kt) {
    const int k0 = kt * 64;
#pragma unroll
    for (int i = 0; i < 4; ++i) {
      int r = i * 32 + w * 8 + lr;
      int sch = lch ^ (r & 7);
      gload_lds16(A + (size_t)(tileM + r) * 1024 + k0 + sch * 8, Alds + i * 2048 + w * 512);
      gload_lds16(Bt + (size_t)(tileN + r) * 1024 + k0 + sch * 8, Blds + i * 2048 + w * 512);
    }
    __syncthreads();
    bf16x8 af[4][2], bfr[4][2];
#pragma unroll
    for (int m = 0; m < 4; ++m) {
#pragma unroll
      for (int kk = 0; kk < 2; ++kk) {
        int row = wm * 64 + m * 16 + (l & 15);
        int ch = ((l >> 4) + kk * 4) ^ (row & 7);
        af[m][kk] = *(const bf16x8*)(Alds + row * 64 + ch * 8);
        int rowb = wn * 64 + m * 16 + (l & 15);
        int chb = ((l >> 4) + kk * 4) ^ (rowb & 7);
        bfr[m][kk] = *(const bf16x8*)(Blds + rowb * 64 + chb * 8);
      }
    }
#pragma unroll
    for (int m = 0; m < 4; ++m)
#pragma unroll
      for (int n = 0; n < 4; ++n)
#pragma unroll
        for (int kk = 0; kk < 2; ++kk)
          acc[m][n] = __builtin_amdgcn_mfma_f32_16x16x32_bf16(af[m][kk], bfr[n][kk], acc[m][n], 0, 0, 0);
    __syncthreads();
  }
#pragma unroll
  for (int m = 0; m < 4; ++m) {
    int row0 = tileM + wm * 64 + m * 16 + ((l >> 4) << 2);
#pragma unroll
    for (int n = 0; n < 4; ++n) {
      int col = tileN + wn * 64 + n * 16 + (l & 15);
#pragma unroll
      for (int q = 0; q < 4; ++q) {
        if (OUT_BF16)
          ((u16*)Cout)[zo * 4194304 + (size_t)(row0 + q) * 1024 + col] = f2bf(acc[m][n][q]);
        else
          ((float*)Cout)[(size_t)(row0 + q) * 1024 + col] = acc[m][n][q];
      }
    }
  }
}

// ---------------- transpose Vi[4096][1024] -> Vt[(bh*64+dk)][2048] ----------------
__global__ __launch_bounds__(256) void transposeV_kernel(const u16* __restrict__ Vi,
                                                         u16* __restrict__ Vt) {
  __shared__ __align__(16) u16 tl[64][72];
  const int tid = threadIdx.x;
  const int st = blockIdx.x * 64;
  const int bh = blockIdx.y;
  const int b = bh >> 4, h = bh & 15;
#pragma unroll
  for (int i = 0; i < 2; ++i) {
    int idx = i * 256 + tid;
    int s = idx >> 3, ch = idx & 7;
    const u16* src = Vi + (size_t)(b * 2048 + st + s) * 1024 + h * 64 + ch * 8;
    u32x2 a = *(const u32x2*)src;
    u32x2 bb = *(const u32x2*)(src + 4);
    *(u32x2*)&tl[s][ch * 8] = a;
    *(u32x2*)&tl[s][ch * 8 + 4] = bb;
  }
  __syncthreads();
#pragma unroll
  for (int i = 0; i < 2; ++i) {
    int idx = i * 256 + tid;
    int dk = idx >> 3, ch = idx & 7;
    u32x4 outv;
    u16* tp = (u16*)&outv;
#pragma unroll
    for (int j = 0; j < 8; ++j) tp[j] = tl[ch * 8 + j][dk];
    *(u32x4*)(Vt + ((size_t)bh * 64 + dk) * 2048 + st + ch * 8) = outv;
  }
}

// ---------------- flash attention: 1 wave / 32 q-rows, K/V direct from L2 ----------------
__global__ __launch_bounds__(64, 2) void attn_kernel(const u16* __restrict__ Qi,
                                                     const u16* __restrict__ Ki,
                                                     const u16* __restrict__ Vt,
                                                     u16* __restrict__ Hd) {
  __shared__ __align__(16) u16 Plds[2][16 * 72];  // per-tile P [16 q][72 t-padded]
  const int l = threadIdx.x;
  const int g = l >> 4, x = l & 15;
  // bijective XCD chunk swizzle: 2048 blocks, XCD d%8 gets 256 contiguous (=4 bh)
  const int d = blockIdx.x;
  const int orig = (d & 7) * 256 + (d >> 3);
  const int bh = orig >> 6;
  const int qt = (orig & 63) * 32;
  const int b = bh >> 4, h = bh & 15;

  const u16* Kbase = Ki + (size_t)b * 2048 * 1024 + h * 64;
  const u16* Vbase = Vt + (size_t)bh * 64 * 2048;

  // Q fragments for 2 q-tiles, pre-scaled by 1/sqrt(dk) = 0.125 (exact)
  bf16x8 qf[2][2];
#pragma unroll
  for (int u = 0; u < 2; ++u) {
    int srow = qt + u * 16 + x;
    const u16* qp = Qi + (size_t)(b * 2048 + srow) * 1024 + h * 64 + g * 8;
#pragma unroll
    for (int kk = 0; kk < 2; ++kk) {
      u32x4 t4 = *(const u32x4*)(qp + kk * 32);
      u16* tp = (u16*)&t4;
#pragma unroll
      for (int j = 0; j < 8; ++j) tp[j] = f2bf(bf2f(tp[j]) * 0.125f);
      qf[u][kk] = *(bf16x8*)&t4;
    }
  }

  f32x4 oacc[2][4] = {};
  float m_r[2][4], l_r[2][4];
#pragma unroll
  for (int u = 0; u < 2; ++u)
#pragma unroll
    for (int q = 0; q < 4; ++q) { m_r[u][q] = -1e30f; l_r[u][q] = 0.f; }

  auto loadK = [&](bf16x8 (&kr)[8], int kt) {
#pragma unroll
    for (int f = 0; f < 4; ++f)
#pragma unroll
      for (int kk = 0; kk < 2; ++kk)
        kr[f * 2 + kk] = *(const bf16x8*)(Kbase + (size_t)(kt * 64 + f * 16 + x) * 1024 + kk * 32 + g * 8);
  };

  auto step = [&](const bf16x8 (&kin)[8], bf16x8 (&knx)[8], int kt) {
    // V fragments for this tile (consumed after QK+softmax -> latency hidden)
    bf16x8 vr[8];
#pragma unroll
    for (int c = 0; c < 4; ++c)
#pragma unroll
      for (int th = 0; th < 2; ++th)
        vr[c * 2 + th] = *(const bf16x8*)(Vbase + (size_t)(c * 16 + x) * 2048 + kt * 64 + th * 32 + g * 8);
    // prefetch next K tile
    if (kt + 1 < 32) loadK(knx, kt + 1);

#pragma unroll
    for (int u = 0; u < 2; ++u) {
      // S = Q K^T
      f32x4 sacc[4] = {};
      __builtin_amdgcn_s_setprio(1);
#pragma unroll
      for (int f = 0; f < 4; ++f)
#pragma unroll
        for (int kk = 0; kk < 2; ++kk)
          sacc[f] = __builtin_amdgcn_mfma_f32_16x16x32_bf16(qf[u][kk], kin[f * 2 + kk], sacc[f], 0, 0, 0);
      __builtin_amdgcn_s_setprio(0);

      // online softmax: rows q = g*4+qreg (of tile u), cols t = f*16+x
      float cur_m[4];
#pragma unroll
      for (int q = 0; q < 4; ++q)
        cur_m[q] = rmax16(fmaxf(fmaxf(sacc[0][q], sacc[1][q]), fmaxf(sacc[2][q], sacc[3][q])));

      float need = -1e30f;
#pragma unroll
      for (int q = 0; q < 4; ++q) need = fmaxf(need, cur_m[q] - m_r[u][q]);
      if (__any(need > 8.f)) {  // defer-rescale
#pragma unroll
        for (int q = 0; q < 4; ++q) {
          float mn = fmaxf(m_r[u][q], cur_m[q]);
          float al = __expf(m_r[u][q] - mn);
          m_r[u][q] = mn;
          l_r[u][q] *= al;
#pragma unroll
          for (int c = 0; c < 4; ++c) oacc[u][c][q] *= al;
        }
      }

      float rs[4] = {0.f, 0.f, 0.f, 0.f};
      u16* Pw = Plds[u];
#pragma unroll
      for (int f = 0; f < 4; ++f)
#pragma unroll
        for (int q = 0; q < 4; ++q) {
          float p = __expf(sacc[f][q] - m_r[u][q]);
          rs[q] += p;
          Pw[(g * 4 + q) * 72 + f * 16 + x] = f2bf(p);
        }
#pragma unroll
      for (int q = 0; q < 4; ++q) l_r[u][q] += rsum16(rs[q]);
    }

    // O += P V for both tiles (P LDS writes drained by compiler waitcnt)
    __builtin_amdgcn_s_setprio(1);
#pragma unroll
    for (int u = 0; u < 2; ++u) {
      const u16* Pw = Plds[u];
      bf16x8 pf0 = *(const bf16x8*)(Pw + x * 72 + g * 8);
      bf16x8 pf1 = *(const bf16x8*)(Pw + x * 72 + g * 8 + 32);
#pragma unroll
      for (int c = 0; c < 4; ++c) {
        oacc[u][c] = __builtin_amdgcn_mfma_f32_16x16x32_bf16(pf0, vr[c * 2 + 0], oacc[u][c], 0, 0, 0);
        oacc[u][c] = __builtin_amdgcn_mfma_f32_16x16x32_bf16(pf1, vr[c * 2 + 1], oacc[u][c], 0, 0, 0);
      }
    }
    __builtin_amdgcn_s_setprio(0);
  };

  bf16x8 kA[8], kB[8];
  loadK(kA, 0);
  for (int kt2 = 0; kt2 < 16; ++kt2) {
    step(kA, kB, 2 * kt2);
    step(kB, kA, 2 * kt2 + 1);
  }

  // epilogue: normalize, write headi in [B][H][S][DK] flat layout
#pragma unroll
  for (int u = 0; u < 2; ++u)
#pragma unroll
    for (int c = 0; c < 4; ++c) {
      int dk = c * 16 + x;
#pragma unroll
      for (int q = 0; q < 4; ++q) {
        int srow = qt + u * 16 + g * 4 + q;
        Hd[((size_t)bh * 2048 + srow) * 64 + dk] = f2bf(oacc[u][c][q] / l_r[u][q]);
      }
    }
}

// ---------------- launch ----------------
extern "C" void kernel_launch(void* const* d_in, const int* in_sizes, int n_in,
                              void* d_out, int out_size, void* d_ws, size_t ws_size,
                              hipStream_t stream) {
  const float* Q = (const float*)d_in[0];
  const float* K = (const float*)d_in[1];
  const float* V = (const float*)d_in[2];
  const float* WQ = (const float*)d_in[3];
  const float* WK = (const float*)d_in[4];
  const float* WV = (const float*)d_in[5];
  const float* WO = (const float*)d_in[6];
  float* out = (float*)d_out;

  size_t off = 0;
  char* ws = (char*)d_ws;
  auto nxt = [&](size_t n) { void* p = ws + off; off += (n + 255) & ~(size_t)255; return p; };
  u16* Qb = (u16*)nxt(3ull * 4096 * 1024 * 2);   // Qb,Kb,Vb contiguous
  u16* Qi = (u16*)nxt(3ull * 4096 * 1024 * 2);   // Qi,Ki,Vi contiguous
  u16* Vtb = (u16*)nxt(4096ull * 1024 * 2);
  u16* Hd = (u16*)nxt(4096ull * 1024 * 2);
  u16* Wt = (u16*)nxt(3ull * 1048576 * 2);
  u16* Wot = (u16*)nxt(1048576ull * 2);
  u16* Ki = Qi + 4194304;
  u16* Vi = Qi + 2 * 4194304;

  prep_kernel<<<4096, 256, 0, stream>>>(Q, K, V, WQ, WK, WV, WO, Qb, Qb + 4194304,
                                        Qb + 2 * 4194304, Wt, Wot);

  // fused Q/K/V projections: z picks (A, W, C) triple
  gemm_kernel<1><<<dim3(32, 8, 3), 256, 0, stream>>>(Qb, Wt, Qi);

  transposeV_kernel<<<dim3(32, 32), 256, 0, stream>>>(Vi, Vtb);

  attn_kernel<<<2048, 64, 0, stream>>>(Qi, Ki, Vtb, Hd);

  gemm_kernel<0><<<dim3(32, 8, 1), 256, 0, stream>>>(Hd, Wot, out);
}

// Round 5
// 215.772 us; speedup vs baseline: 1.0235x; 1.0235x over previous
//
#include <hip/hip_runtime.h>
#include <hip/hip_bf16.h>
#include <stdint.h>

typedef unsigned short u16;
typedef unsigned int u32;
typedef __attribute__((ext_vector_type(4))) float f32x4;
typedef __attribute__((ext_vector_type(16))) float f32x16;
typedef __attribute__((ext_vector_type(8))) short bf16x8;
typedef __attribute__((ext_vector_type(4))) unsigned int u32x4;
typedef __attribute__((ext_vector_type(2))) unsigned int u32x2;

#define DEV __device__ __forceinline__

DEV u16 f2bf(float f) {
  union { float f; uint32_t u; } v; v.f = f;
  uint32_t u = v.u;
  return (u16)((u + 0x7fffu + ((u >> 16) & 1u)) >> 16);
}
DEV float bf2f(u16 h) {
  union { uint32_t u; float f; } v; v.u = ((uint32_t)h) << 16;
  return v.f;
}

DEV u32 cvtpk(float a, float b) {  // D.lo = bf16(a), D.hi = bf16(b), RNE
  u32 r;
  asm("v_cvt_pk_bf16_f32 %0, %1, %2" : "=v"(r) : "v"(a), "v"(b));
  return r;
}

DEV void gload_lds16(const u16* g, u16* l) {
  __builtin_amdgcn_global_load_lds(
      (const __attribute__((address_space(1))) void*)g,
      (__attribute__((address_space(3))) void*)l, 16, 0, 0);
}

// ---------------- prep: fp32 -> bf16 + transposed weights ----------------
__global__ __launch_bounds__(256) void prep_kernel(
    const float* __restrict__ Q, const float* __restrict__ K, const float* __restrict__ V,
    const float* __restrict__ WQ, const float* __restrict__ WK, const float* __restrict__ WV,
    const float* __restrict__ WO,
    u16* __restrict__ Qb, u16* __restrict__ Kb, u16* __restrict__ Vb,
    u16* __restrict__ Wt, u16* __restrict__ Wot) {
  const int i = blockIdx.x * 256 + threadIdx.x;  // 1,048,576 threads
#pragma unroll
  for (int it = 0; it < 3; ++it) {
    int idx = it * 1048576 + i;
    int which = idx >> 20, j = idx & 1048575;
    const float* src = which == 0 ? Q : (which == 1 ? K : V);
    u16* dst = which == 0 ? Qb : (which == 1 ? Kb : Vb);
    float4 v = ((const float4*)src)[j];
    u32x2 pk;
    pk[0] = (u32)f2bf(v.x) | ((u32)f2bf(v.y) << 16);
    pk[1] = (u32)f2bf(v.z) | ((u32)f2bf(v.w) << 16);
    *(u32x2*)(dst + (size_t)j * 4) = pk;
  }
#pragma unroll
  for (int it = 0; it < 4; ++it) {
    int idx = it * 1048576 + i;
    if (idx < 3145728) {
      int p = idx >> 20, r = idx & 1048575;
      int n = r >> 10, d = r & 1023;
      int h = n >> 6, k = n & 63;
      const float* src = p == 0 ? WQ : (p == 1 ? WK : WV);
      Wt[idx] = f2bf(src[(h * 1024 + d) * 64 + k]);
    } else {
      int j = idx - 3145728;
      int c = j >> 10, k = j & 1023;
      Wot[j] = f2bf(WO[k * 1024 + c]);
    }
  }
}

// ---------------- GEMM: C[4096][1024] = A[4096][1024] * Bt^T, z-batched ----------------
template <int OUT_BF16>
__global__ __launch_bounds__(256, 2) void gemm_kernel(const u16* __restrict__ A,
                                                      const u16* __restrict__ Bt,
                                                      void* __restrict__ Cout) {
  __shared__ __align__(16) u16 Alds[128 * 64];
  __shared__ __align__(16) u16 Blds[128 * 64];
  const size_t zo = blockIdx.z;
  A += zo * 4194304;
  Bt += zo * 1048576;
  const int tid = threadIdx.x;
  const int l = tid & 63, w = tid >> 6;
  const int wm = w >> 1, wn = w & 1;
  const int tileM = blockIdx.x * 128, tileN = blockIdx.y * 128;
  const int lr = l >> 3, lch = l & 7;

  f32x4 acc[4][4] = {};

  for (int kt = 0; kt < 16; ++kt) {
    const int k0 = kt * 64;
#pragma unroll
    for (int i = 0; i < 4; ++i) {
      int r = i * 32 + w * 8 + lr;
      int sch = lch ^ (r & 7);
      gload_lds16(A + (size_t)(tileM + r) * 1024 + k0 + sch * 8, Alds + i * 2048 + w * 512);
      gload_lds16(Bt + (size_t)(tileN + r) * 1024 + k0 + sch * 8, Blds + i * 2048 + w * 512);
    }
    __syncthreads();
    bf16x8 af[4][2], bfr[4][2];
#pragma unroll
    for (int m = 0; m < 4; ++m) {
#pragma unroll
      for (int kk = 0; kk < 2; ++kk) {
        int row = wm * 64 + m * 16 + (l & 15);
        int ch = ((l >> 4) + kk * 4) ^ (row & 7);
        af[m][kk] = *(const bf16x8*)(Alds + row * 64 + ch * 8);
        int rowb = wn * 64 + m * 16 + (l & 15);
        int chb = ((l >> 4) + kk * 4) ^ (rowb & 7);
        bfr[m][kk] = *(const bf16x8*)(Blds + rowb * 64 + chb * 8);
      }
    }
#pragma unroll
    for (int m = 0; m < 4; ++m)
#pragma unroll
      for (int n = 0; n < 4; ++n)
#pragma unroll
        for (int kk = 0; kk < 2; ++kk)
          acc[m][n] = __builtin_amdgcn_mfma_f32_16x16x32_bf16(af[m][kk], bfr[n][kk], acc[m][n], 0, 0, 0);
    __syncthreads();
  }
#pragma unroll
  for (int m = 0; m < 4; ++m) {
    int row0 = tileM + wm * 64 + m * 16 + ((l >> 4) << 2);
#pragma unroll
    for (int n = 0; n < 4; ++n) {
      int col = tileN + wn * 64 + n * 16 + (l & 15);
#pragma unroll
      for (int q = 0; q < 4; ++q) {
        if (OUT_BF16)
          ((u16*)Cout)[zo * 4194304 + (size_t)(row0 + q) * 1024 + col] = f2bf(acc[m][n][q]);
        else
          ((float*)Cout)[(size_t)(row0 + q) * 1024 + col] = acc[m][n][q];
      }
    }
  }
}

// ---------------- transpose Vi[4096][1024] -> Vt[(bh*64+dk)][2048] ----------------
__global__ __launch_bounds__(256) void transposeV_kernel(const u16* __restrict__ Vi,
                                                         u16* __restrict__ Vt) {
  __shared__ __align__(16) u16 tl[64][72];
  const int tid = threadIdx.x;
  const int st = blockIdx.x * 64;
  const int bh = blockIdx.y;
  const int b = bh >> 4, h = bh & 15;
#pragma unroll
  for (int i = 0; i < 2; ++i) {
    int idx = i * 256 + tid;
    int s = idx >> 3, ch = idx & 7;
    const u16* src = Vi + (size_t)(b * 2048 + st + s) * 1024 + h * 64 + ch * 8;
    u32x2 a = *(const u32x2*)src;
    u32x2 bb = *(const u32x2*)(src + 4);
    *(u32x2*)&tl[s][ch * 8] = a;
    *(u32x2*)&tl[s][ch * 8 + 4] = bb;
  }
  __syncthreads();
#pragma unroll
  for (int i = 0; i < 2; ++i) {
    int idx = i * 256 + tid;
    int dk = idx >> 3, ch = idx & 7;
    u32x4 outv;
    u16* tp = (u16*)&outv;
#pragma unroll
    for (int j = 0; j < 8; ++j) tp[j] = tl[ch * 8 + j][dk];
    *(u32x4*)(Vt + ((size_t)bh * 64 + dk) * 2048 + st + ch * 8) = outv;
  }
}

// ---------------- flash attention: 32x32 swapped-QK, in-register softmax ----------------
// Block = 4 waves = 2 q-blocks(32 rows) x 2 kv-halves(16 tiles of 64).
// Lane owns q = l&31 in the S-domain (D col = lane&31); O-regs have
// q(reg) = (reg&3)+8*(reg>>2)+4*(lane>>5)  [verified m74/m101].
__global__ __launch_bounds__(256, 3) void attn_kernel(const u16* __restrict__ Qi,
                                                      const u16* __restrict__ Ki,
                                                      const u16* __restrict__ Vt,
                                                      u16* __restrict__ Hd) {
  __shared__ __align__(16) u16 Pl[4][32 * 72];     // per-wave P [32 q][72 t-pad]
  __shared__ __align__(16) float Obuf[2][32][64];  // per-q-block combine buffer
  __shared__ float mlds[2][2][32], llds[2][2][32], fnl[2][2][32], alds[4][32];
  const int tid = threadIdx.x;
  const int l = tid & 63, w = tid >> 6;
  const int qb = w >> 1, kvh = w & 1;
  const int lq = l & 31, hi = l >> 5;
  // bijective XCD chunk swizzle: 1024 blocks, XCD dd%8 gets 128 contiguous (=4 bh)
  const int dd = blockIdx.x;
  const int orig = (dd & 7) * 128 + (dd >> 3);
  const int bh = orig >> 5;
  const int qt = (orig & 31) * 64 + qb * 32;
  const int b = bh >> 4, h = bh & 15;

  const u16* Kb = Ki + (size_t)b * 2048 * 1024 + h * 64;
  const u16* Vb = Vt + (size_t)bh * 64 * 2048;
  u16* Pw = Pl[w];

  // Q B-frags (col q = lq, k = s*16 + hi*8), prescaled by log2(e)/8 (exp2 domain)
  bf16x8 qf[4];
  {
    const u16* qp = Qi + (size_t)(b * 2048 + qt + lq) * 1024 + h * 64 + hi * 8;
#pragma unroll
    for (int s = 0; s < 4; ++s) {
      u32x4 t4 = *(const u32x4*)(qp + s * 16);
      u16* tp = (u16*)&t4;
#pragma unroll
      for (int j = 0; j < 8; ++j) tp[j] = f2bf(bf2f(tp[j]) * 0.1803368867f);
      qf[s] = *(bf16x8*)&t4;
    }
  }

  f32x16 o0 = {}, o1 = {};
  float m_r = -1e30f, l_r = 0.f;

  for (int it = 0; it < 16; ++it) {
    const int kt = kvh * 16 + it;
    // K A-frags (row t, k-chunk) and V B-frags (col d, t-chunk) direct from L2
    bf16x8 kf[8], vf[8];
    {
      const u16* kp = Kb + (size_t)(kt * 64 + lq) * 1024 + hi * 8;
#pragma unroll
      for (int s = 0; s < 4; ++s) {
        kf[s] = *(const bf16x8*)(kp + s * 16);
        kf[4 + s] = *(const bf16x8*)(kp + (size_t)32 * 1024 + s * 16);
      }
      const u16* vp = Vb + (size_t)lq * 2048 + kt * 64 + hi * 8;
#pragma unroll
      for (int s = 0; s < 4; ++s) {
        vf[s] = *(const bf16x8*)(vp + s * 16);
        vf[4 + s] = *(const bf16x8*)(vp + (size_t)32 * 2048 + s * 16);
      }
    }

    // S^T = K Q^T : D[t][q], lane col q = lq
    f32x16 s0 = {}, s1 = {};
    __builtin_amdgcn_s_setprio(1);
#pragma unroll
    for (int s = 0; s < 4; ++s)
      s0 = __builtin_amdgcn_mfma_f32_32x32x16_bf16(kf[s], qf[s], s0, 0, 0, 0);
#pragma unroll
    for (int s = 0; s < 4; ++s)
      s1 = __builtin_amdgcn_mfma_f32_32x32x16_bf16(kf[4 + s], qf[s], s1, 0, 0, 0);
    __builtin_amdgcn_s_setprio(0);

    // in-register row max (lane has 32 of 64 t for its q; partner lane l^32 has rest)
    float mx = s0[0];
#pragma unroll
    for (int r = 1; r < 16; ++r) mx = fmaxf(mx, s0[r]);
#pragma unroll
    for (int r = 0; r < 16; ++r) mx = fmaxf(mx, s1[r]);
    mx = fmaxf(mx, __shfl_xor(mx, 32, 64));

    if (__any(mx - m_r > 8.f)) {  // defer-rescale (log2 domain, P <= 2^8)
      float mn = fmaxf(m_r, mx);
      float al = exp2f(m_r - mn);
      m_r = mn;
      l_r *= al;
      alds[w][lq] = al;  // redistribute to O-reg layout via LDS broadcast
#pragma unroll
      for (int r = 0; r < 16; ++r) {
        float a = alds[w][(r & 3) + 8 * (r >> 2) + 4 * hi];
        o0[r] *= a;
        o1[r] *= a;
      }
    }

    // P = exp2(S - m), packed bf16 pairs into LDS [32 q][72 t]
    float rs = 0.f;
#pragma unroll
    for (int tt = 0; tt < 2; ++tt) {
#pragma unroll
      for (int j = 0; j < 4; ++j) {
#pragma unroll
        for (int cp = 0; cp < 2; ++cp) {
          int r0 = 4 * j + 2 * cp;
          float e0 = tt ? s1[r0] : s0[r0];
          float e1 = tt ? s1[r0 + 1] : s0[r0 + 1];
          float p0 = exp2f(e0 - m_r);
          float p1 = exp2f(e1 - m_r);
          rs += p0 + p1;
          // t_local = (2cp..) + 8j + 4hi (+32 tt); u16 index = lq*72 + t
          *(u32*)(Pw + lq * 72 + tt * 32 + 8 * j + 4 * hi + 2 * cp) = cvtpk(p0, p1);
        }
      }
    }
    rs += __shfl_xor(rs, 32, 64);
    l_r += rs;

    // PV: A-frag = P rows (lane row q = lq, t-chunk s*16 + hi*8)
    bf16x8 pa[4];
#pragma unroll
    for (int s = 0; s < 4; ++s)
      pa[s] = *(const bf16x8*)(Pw + lq * 72 + s * 16 + hi * 8);
    __builtin_amdgcn_s_setprio(1);
#pragma unroll
    for (int s = 0; s < 4; ++s)
      o0 = __builtin_amdgcn_mfma_f32_32x32x16_bf16(pa[s], vf[s], o0, 0, 0, 0);
#pragma unroll
    for (int s = 0; s < 4; ++s)
      o1 = __builtin_amdgcn_mfma_f32_32x32x16_bf16(pa[s], vf[4 + s], o1, 0, 0, 0);
    __builtin_amdgcn_s_setprio(0);
  }

  // ---- combine the two kv-halves ----
  mlds[qb][kvh][lq] = m_r;
  llds[qb][kvh][lq] = l_r;
  __syncthreads();
  {
    float m_o = mlds[qb][kvh ^ 1][lq];
    float l_o = llds[qb][kvh ^ 1][lq];
    float M = fmaxf(m_r, m_o);
    float L = l_r * exp2f(m_r - M) + l_o * exp2f(m_o - M);
    fnl[qb][kvh][lq] = exp2f(m_r - M) / L;
  }
  __syncthreads();
#pragma unroll
  for (int r = 0; r < 16; ++r) {
    float fac = fnl[qb][kvh][(r & 3) + 8 * (r >> 2) + 4 * hi];
    o0[r] *= fac;
    o1[r] *= fac;
  }
  if (kvh == 1) {
#pragma unroll
    for (int r = 0; r < 16; ++r) {
      int qr = (r & 3) + 8 * (r >> 2) + 4 * hi;
      Obuf[qb][qr][lq] = o0[r];
      Obuf[qb][qr][32 + lq] = o1[r];
    }
  }
  __syncthreads();
  if (kvh == 0) {
#pragma unroll
    for (int r = 0; r < 16; ++r) {
      int qr = (r & 3) + 8 * (r >> 2) + 4 * hi;
      u16* hp = Hd + ((size_t)bh * 2048 + qt + qr) * 64;
      hp[lq] = f2bf(o0[r] + Obuf[qb][qr][lq]);
      hp[32 + lq] = f2bf(o1[r] + Obuf[qb][qr][32 + lq]);
    }
  }
}

// ---------------- launch ----------------
extern "C" void kernel_launch(void* const* d_in, const int* in_sizes, int n_in,
                              void* d_out, int out_size, void* d_ws, size_t ws_size,
                              hipStream_t stream) {
  const float* Q = (const float*)d_in[0];
  const float* K = (const float*)d_in[1];
  const float* V = (const float*)d_in[2];
  const float* WQ = (const float*)d_in[3];
  const float* WK = (const float*)d_in[4];
  const float* WV = (const float*)d_in[5];
  const float* WO = (const float*)d_in[6];
  float* out = (float*)d_out;

  size_t off = 0;
  char* ws = (char*)d_ws;
  auto nxt = [&](size_t n) { void* p = ws + off; off += (n + 255) & ~(size_t)255; return p; };
  u16* Qb = (u16*)nxt(3ull * 4096 * 1024 * 2);   // Qb,Kb,Vb contiguous
  u16* Qi = (u16*)nxt(3ull * 4096 * 1024 * 2);   // Qi,Ki,Vi contiguous
  u16* Vtb = (u16*)nxt(4096ull * 1024 * 2);
  u16* Hd = (u16*)nxt(4096ull * 1024 * 2);
  u16* Wt = (u16*)nxt(3ull * 1048576 * 2);
  u16* Wot = (u16*)nxt(1048576ull * 2);
  u16* Ki = Qi + 4194304;
  u16* Vi = Qi + 2 * 4194304;

  prep_kernel<<<4096, 256, 0, stream>>>(Q, K, V, WQ, WK, WV, WO, Qb, Qb + 4194304,
                                        Qb + 2 * 4194304, Wt, Wot);

  // fused Q/K/V projections: z picks (A, W, C) triple
  gemm_kernel<1><<<dim3(32, 8, 3), 256, 0, stream>>>(Qb, Wt, Qi);

  transposeV_kernel<<<dim3(32, 32), 256, 0, stream>>>(Vi, Vtb);

  attn_kernel<<<1024, 256, 0, stream>>>(Qi, Ki, Vtb, Hd);

  gemm_kernel<0><<<dim3(32, 8, 1), 256, 0, stream>>>(Hd, Wot, out);
}